// Round 1
// baseline (222.340 us; speedup 1.0000x reference)
//
#include <hip/hip_runtime.h>

#define BROWS 16384
#define DDIM  512
#define NEXP  16
#define HDIM  128
#define ODIM  512

typedef __attribute__((ext_vector_type(8))) short bf16x8;
typedef __attribute__((ext_vector_type(4))) float f32x4;

static __device__ __forceinline__ unsigned short f2bf(float f) {
    union { float f; unsigned u; } v; v.f = f;
    unsigned r = v.u + 0x7fffu + ((v.u >> 16) & 1u);
    return (unsigned short)(r >> 16);
}
static __device__ __forceinline__ float bf2f(unsigned short h) {
    union { unsigned u; float f; } v; v.u = ((unsigned)h) << 16;
    return v.f;
}

// ---------------- x -> bf16 ----------------
__global__ __launch_bounds__(256)
void conv_x_kernel(const float* __restrict__ x, unsigned short* __restrict__ xb, int n8) {
    int i = blockIdx.x * 256 + threadIdx.x;
    if (i >= n8) return;
    const float4* p = reinterpret_cast<const float4*>(x) + (size_t)i * 2;
    float4 a = p[0], b = p[1];
    bf16x8 v;
    v[0] = (short)f2bf(a.x); v[1] = (short)f2bf(a.y);
    v[2] = (short)f2bf(a.z); v[3] = (short)f2bf(a.w);
    v[4] = (short)f2bf(b.x); v[5] = (short)f2bf(b.y);
    v[6] = (short)f2bf(b.z); v[7] = (short)f2bf(b.w);
    *reinterpret_cast<bf16x8*>(xb + (size_t)i * 8) = v;
}

// ---------------- transpose weights to bf16 [C][R] ----------------
__global__ __launch_bounds__(256)
void transpose_to_bf16(const float* __restrict__ in, unsigned short* __restrict__ out, int R, int C) {
    __shared__ float tile[32][33];
    int e = blockIdx.z;
    in  += (size_t)e * R * C;
    out += (size_t)e * R * C;
    int c0 = blockIdx.x * 32, r0 = blockIdx.y * 32;
    for (int i = threadIdx.y; i < 32; i += 8)
        tile[i][threadIdx.x] = in[(size_t)(r0 + i) * C + c0 + threadIdx.x];
    __syncthreads();
    for (int i = threadIdx.y; i < 32; i += 8)
        out[(size_t)(c0 + i) * R + r0 + threadIdx.x] = f2bf(tile[threadIdx.x][i]);
}

// ---------------- gating ----------------
__global__ __launch_bounds__(128)
void gate_kernel(const float* __restrict__ x, const float* __restrict__ gW,
                 const float* __restrict__ gb,
                 int* cnt, float* ent_acc, int* bucket, int* topk_e, float* topk_w) {
    __shared__ __align__(16) float gw[DDIM * NEXP];
    __shared__ __align__(16) float xs[8][516];
    __shared__ float sc[8][17];
    __shared__ float entl[8];
    int tid = threadIdx.x;
    int rb = blockIdx.x * 8;

    for (int i = tid; i < DDIM * NEXP; i += 128) gw[i] = gW[i];
    for (int i = tid; i < 8 * DDIM; i += 128) {
        int r = i >> 9, d = i & 511;
        xs[r][d] = x[(size_t)(rb + r) * DDIM + d];
    }
    __syncthreads();

    int r = tid >> 4, e = tid & 15;
    float s = gb[e];
    const float4* xr = reinterpret_cast<const float4*>(&xs[r][0]);
    #pragma unroll 8
    for (int d4 = 0; d4 < 128; ++d4) {
        float4 xv = xr[d4];
        int d = d4 * 4;
        s = fmaf(xv.x, gw[d * 16 + e], s);
        s = fmaf(xv.y, gw[d * 16 + 16 + e], s);
        s = fmaf(xv.z, gw[d * 16 + 32 + e], s);
        s = fmaf(xv.w, gw[d * 16 + 48 + e], s);
    }
    sc[r][e] = s;
    __syncthreads();

    if (tid < 8) {
        int row = rb + tid;
        float v0 = -1e30f, v1 = -1e30f; int i0 = 0, i1 = 0;
        for (int k = 0; k < 16; ++k) {
            float sv = sc[tid][k];
            if (sv > v0) { v1 = v0; i1 = i0; v0 = sv; i0 = k; }
            else if (sv > v1) { v1 = sv; i1 = k; }
        }
        float Z = 0.f;
        for (int k = 0; k < 16; ++k) Z += expf(sc[tid][k] - v0);
        float lse = v0 + logf(Z);
        float ent = 0.f;
        for (int k = 0; k < 16; ++k) { float lp = sc[tid][k] - lse; ent -= expf(lp) * lp; }
        entl[tid] = ent;
        float e1w = expf(v1 - v0);
        float w0 = 1.0f / (1.0f + e1w);
        topk_e[row * 2]     = i0;
        topk_e[row * 2 + 1] = i1;
        topk_w[row * 2]     = w0;
        topk_w[row * 2 + 1] = 1.0f - w0;
        int p0 = atomicAdd(&cnt[i0], 1);
        bucket[i0 * BROWS + p0] = (row << 1);
        int p1 = atomicAdd(&cnt[i1], 1);
        bucket[i1 * BROWS + p1] = (row << 1) | 1;
    }
    __syncthreads();
    if (tid == 0) {
        float t = 0.f;
        for (int i = 0; i < 8; ++i) t += entl[i];
        atomicAdd(ent_acc, t);
    }
}

// ---------------- aux loss ----------------
__global__ void aux_kernel(const int* __restrict__ cnt, const float* __restrict__ ent_acc,
                           float* __restrict__ outp) {
    if (threadIdx.x == 0 && blockIdx.x == 0) {
        float lb = 0.f;
        for (int k = 0; k < 16; ++k) {
            float u = (float)cnt[k] * (1.f / 16384.f) - 0.0625f;
            lb += u * u;
        }
        lb *= (1.f / 16.f);
        float ment = ent_acc[0] * (1.f / 16384.f);
        outp[0] = lb - 0.1f * ment;
    }
}

// ---------------- grouped sparse FFN ----------------
// grid.x = NEXP * 256 (tiles of 64 rows); block = 256 (4 waves)
__global__ __launch_bounds__(256, 2)
void ffn_kernel(const unsigned short* __restrict__ xb,
                const unsigned short* __restrict__ w1t,   // [E][H][D] bf16
                const unsigned short* __restrict__ w2t,   // [E][O][H] bf16
                const float* __restrict__ b1, const float* __restrict__ ln_g,
                const float* __restrict__ ln_b,
                const int* __restrict__ cnt, const int* __restrict__ bucket,
                unsigned short* __restrict__ contrib) {
    int e = blockIdx.x >> 8;
    int t = blockIdx.x & 255;
    int n = cnt[e];
    int base = t * 64;
    if (base >= n) return;
    int rows = n - base; if (rows > 64) rows = 64;

    __shared__ __align__(16) char smem[65536];

    int tid = threadIdx.x;
    int wave = tid >> 6, lane = tid & 63;
    int l15 = lane & 15, l4 = lane >> 4;
    const int bbase = e * BROWS + base;

    // ---- stage x tile (64 rows x 512 bf16), XOR-swizzled rows ----
    #pragma unroll
    for (int i = 0; i < 16; ++i) {
        int r = wave * 16 + i;
        int bidx = bbase + ((r < rows) ? r : 0);
        int grow = bucket[bidx] >> 1;
        uint4 v = *reinterpret_cast<const uint4*>(xb + (size_t)grow * DDIM + lane * 8);
        int boff = r * 1024 + ((lane * 16) ^ ((r & 7) << 4));
        *reinterpret_cast<uint4*>(smem + boff) = v;
    }
    __syncthreads();

    // ---- GEMM1: h[64][128] = x_tile @ W1[e] ----
    const unsigned short* w1e = w1t + (size_t)e * HDIM * DDIM;
    f32x4 acc1[4][2];
    #pragma unroll
    for (int r = 0; r < 4; ++r)
        #pragma unroll
        for (int c = 0; c < 2; ++c)
            acc1[r][c] = (f32x4){0.f, 0.f, 0.f, 0.f};

    #pragma unroll
    for (int ks = 0; ks < 16; ++ks) {
        bf16x8 af[4];
        #pragma unroll
        for (int r = 0; r < 4; ++r) {
            int row = r * 16 + l15;
            int boff = row * 1024 + (((ks * 64) + (l4 * 16)) ^ ((row & 7) << 4));
            af[r] = *reinterpret_cast<const bf16x8*>(smem + boff);
        }
        bf16x8 bfg[2];
        #pragma unroll
        for (int c = 0; c < 2; ++c) {
            int col = wave * 32 + c * 16 + l15;
            bfg[c] = *reinterpret_cast<const bf16x8*>(w1e + (size_t)col * DDIM + ks * 32 + l4 * 8);
        }
        #pragma unroll
        for (int r = 0; r < 4; ++r)
            #pragma unroll
            for (int c = 0; c < 2; ++c)
                acc1[r][c] = __builtin_amdgcn_mfma_f32_16x16x32_bf16(af[r], bfg[c], acc1[r][c], 0, 0, 0);
    }
    __syncthreads();   // xs dead; reuse smem

    // ---- bias + exact GELU -> hbuf f32 [64][128] at smem[0..32767] ----
    float* hbuf = reinterpret_cast<float*>(smem);
    const float* b1e = b1 + e * HDIM;
    #pragma unroll
    for (int r = 0; r < 4; ++r)
        #pragma unroll
        for (int c = 0; c < 2; ++c)
            #pragma unroll
            for (int i = 0; i < 4; ++i) {
                int row = r * 16 + l4 * 4 + i;
                int col = wave * 32 + c * 16 + l15;
                float v = acc1[r][c][i] + b1e[col];
                v = 0.5f * v * (1.0f + erff(v * 0.70710678118654752f));
                hbuf[row * 128 + col] = v;
            }
    __syncthreads();

    // ---- LayerNorm over H=128, write bf16 swizzled at smem[32768..49151] ----
    {
        int lrow = tid >> 2, q = tid & 3;
        float s = 0.f, ss = 0.f;
        #pragma unroll
        for (int j = 0; j < 32; ++j) {
            float v = hbuf[lrow * 128 + q + j * 4];
            s += v; ss += v * v;
        }
        s  += __shfl_xor(s, 1);  s  += __shfl_xor(s, 2);
        ss += __shfl_xor(ss, 1); ss += __shfl_xor(ss, 2);
        float mean = s * 0.0078125f;
        float var  = fmaf(-mean, mean, ss * 0.0078125f);
        float rstd = rsqrtf(var + 1e-5f);
        const float* lge = ln_g + e * HDIM;
        const float* lbe = ln_b + e * HDIM;
        #pragma unroll
        for (int j = 0; j < 32; ++j) {
            int col = q + j * 4;
            float v = (hbuf[lrow * 128 + col] - mean) * rstd * lge[col] + lbe[col];
            int boff = 32768 + lrow * 256 + (((col * 2)) ^ ((lrow & 7) << 4));
            *reinterpret_cast<unsigned short*>(smem + boff) = f2bf(v);
        }
    }
    __syncthreads();

    // ---- GEMM2: contrib[64][512] = h_ln @ W2[e]; two column halves ----
    const unsigned short* w2e = w2t + (size_t)e * ODIM * HDIM;
    #pragma unroll 1
    for (int half = 0; half < 2; ++half) {
        f32x4 acc2[4][4];
        #pragma unroll
        for (int r = 0; r < 4; ++r)
            #pragma unroll
            for (int c = 0; c < 4; ++c)
                acc2[r][c] = (f32x4){0.f, 0.f, 0.f, 0.f};

        #pragma unroll
        for (int ks = 0; ks < 4; ++ks) {
            bf16x8 af[4];
            #pragma unroll
            for (int r = 0; r < 4; ++r) {
                int row = r * 16 + l15;
                int boff = 32768 + row * 256 + (((ks * 64) + (l4 * 16)) ^ ((row & 7) << 4));
                af[r] = *reinterpret_cast<const bf16x8*>(smem + boff);
            }
            bf16x8 bfg[4];
            #pragma unroll
            for (int c = 0; c < 4; ++c) {
                int col = wave * 128 + half * 64 + c * 16 + l15;
                bfg[c] = *reinterpret_cast<const bf16x8*>(w2e + (size_t)col * HDIM + ks * 32 + l4 * 8);
            }
            #pragma unroll
            for (int r = 0; r < 4; ++r)
                #pragma unroll
                for (int c = 0; c < 4; ++c)
                    acc2[r][c] = __builtin_amdgcn_mfma_f32_16x16x32_bf16(af[r], bfg[c], acc2[r][c], 0, 0, 0);
        }
        // epilogue: store raw contributions (weights applied in combine)
        #pragma unroll
        for (int r = 0; r < 4; ++r)
            #pragma unroll
            for (int i = 0; i < 4; ++i) {
                int lrow = r * 16 + l4 * 4 + i;
                if (lrow < rows) {
                    int rs = bucket[bbase + lrow];   // (row<<1)|slot
                    #pragma unroll
                    for (int c = 0; c < 4; ++c) {
                        int col = wave * 128 + half * 64 + c * 16 + l15;
                        contrib[(size_t)rs * ODIM + col] = f2bf(acc2[r][c][i]);
                    }
                }
            }
    }
}

// ---------------- combine top-2 ----------------
__global__ __launch_bounds__(256)
void combine_kernel(const unsigned short* __restrict__ contrib, const int* __restrict__ topk_e,
                    const float* __restrict__ topk_w, const float* __restrict__ b2,
                    float* __restrict__ out) {
    int idx = blockIdx.x * 256 + threadIdx.x;
    int row = idx >> 6;
    int cb = (idx & 63) << 3;
    float w0 = topk_w[row * 2], w1 = topk_w[row * 2 + 1];
    int e0 = topk_e[row * 2], e1 = topk_e[row * 2 + 1];
    bf16x8 c0 = *reinterpret_cast<const bf16x8*>(contrib + (size_t)row * 1024 + cb);
    bf16x8 c1 = *reinterpret_cast<const bf16x8*>(contrib + (size_t)row * 1024 + 512 + cb);
    const float* b20 = b2 + e0 * ODIM + cb;
    const float* b21 = b2 + e1 * ODIM + cb;
    float res[8];
    #pragma unroll
    for (int j = 0; j < 8; ++j)
        res[j] = w0 * (bf2f((unsigned short)c0[j]) + b20[j]) + w1 * (bf2f((unsigned short)c1[j]) + b21[j]);
    float4 o0 = {res[0], res[1], res[2], res[3]};
    float4 o1 = {res[4], res[5], res[6], res[7]};
    *reinterpret_cast<float4*>(out + (size_t)row * ODIM + cb) = o0;
    *reinterpret_cast<float4*>(out + (size_t)row * ODIM + cb + 4) = o1;
}

extern "C" void kernel_launch(void* const* d_in, const int* in_sizes, int n_in,
                              void* d_out, int out_size, void* d_ws, size_t ws_size,
                              hipStream_t stream) {
    const float* x    = (const float*)d_in[0];
    const float* gW   = (const float*)d_in[1];
    const float* gb   = (const float*)d_in[2];
    const float* W1   = (const float*)d_in[3];
    const float* b1   = (const float*)d_in[4];
    const float* ln_g = (const float*)d_in[5];
    const float* ln_b = (const float*)d_in[6];
    const float* W2   = (const float*)d_in[7];
    const float* b2   = (const float*)d_in[8];
    float* out = (float*)d_out;

    char* ws = (char*)d_ws;
    int*   cnt     = (int*)(ws);                       // 64 B
    float* ent_acc = (float*)(ws + 64);                // 4 B
    int*   topk_e  = (int*)(ws + 256);                 // 128 KB
    float* topk_w  = (float*)(ws + 256 + 131072);      // 128 KB
    int*   bucket  = (int*)(ws + 262400);              // 1 MB
    unsigned short* xb      = (unsigned short*)(ws + 1310976);   // 16 MB
    unsigned short* w1t     = (unsigned short*)(ws + 18088192);  // 2 MB
    unsigned short* w2t     = (unsigned short*)(ws + 20185344);  // 2 MB
    unsigned short* contrib = (unsigned short*)(ws + 22282496);  // 32 MB

    hipMemsetAsync(ws, 0, 256, stream);

    conv_x_kernel<<<4096, 256, 0, stream>>>(x, xb, (BROWS * DDIM) / 8);
    transpose_to_bf16<<<dim3(HDIM / 32, DDIM / 32, NEXP), dim3(32, 8), 0, stream>>>(W1, w1t, DDIM, HDIM);
    transpose_to_bf16<<<dim3(ODIM / 32, HDIM / 32, NEXP), dim3(32, 8), 0, stream>>>(W2, w2t, HDIM, ODIM);
    gate_kernel<<<BROWS / 8, 128, 0, stream>>>(x, gW, gb, cnt, ent_acc, bucket, topk_e, topk_w);
    aux_kernel<<<1, 64, 0, stream>>>(cnt, ent_acc, out + (out_size - 1));
    ffn_kernel<<<NEXP * 256, 256, 0, stream>>>(xb, w1t, w2t, b1, ln_g, ln_b, cnt, bucket, contrib);
    combine_kernel<<<(BROWS * ODIM / 8) / 256, 256, 0, stream>>>(contrib, topk_e, topk_w, b2, out);
}

// Round 2
// 131.162 us; speedup vs baseline: 1.6952x; 1.6952x over previous
//
#include <hip/hip_runtime.h>

#define BROWS 16384
#define DDIM  512
#define NEXP  16
#define HDIM  128
#define ODIM  512

typedef __attribute__((ext_vector_type(8))) short bf16x8;
typedef __attribute__((ext_vector_type(4))) float f32x4;

static __device__ __forceinline__ unsigned short f2bf(float f) {
    union { float f; unsigned u; } v; v.f = f;
    unsigned r = v.u + 0x7fffu + ((v.u >> 16) & 1u);
    return (unsigned short)(r >> 16);
}
static __device__ __forceinline__ float bf2f(unsigned short h) {
    union { unsigned u; float f; } v; v.u = ((unsigned)h) << 16;
    return v.f;
}

// ---------------- transpose weights to bf16 [C][R] ----------------
__global__ __launch_bounds__(256)
void transpose_to_bf16(const float* __restrict__ in, unsigned short* __restrict__ out, int R, int C) {
    __shared__ float tile[32][33];
    int e = blockIdx.z;
    in  += (size_t)e * R * C;
    out += (size_t)e * R * C;
    int c0 = blockIdx.x * 32, r0 = blockIdx.y * 32;
    for (int i = threadIdx.y; i < 32; i += 8)
        tile[i][threadIdx.x] = in[(size_t)(r0 + i) * C + c0 + threadIdx.x];
    __syncthreads();
    for (int i = threadIdx.y; i < 32; i += 8)
        out[(size_t)(c0 + i) * R + r0 + threadIdx.x] = f2bf(tile[threadIdx.x][i]);
}

// ---------------- gating (fused with x->bf16 conversion) ----------------
// 512 blocks x 256 threads; each block: 32 rows. Each wave: 8 rows.
// Lane split: ds = lane&31 (d-slice), rg = lane>>5 (row parity). Each lane: 4 rows.
__global__ __launch_bounds__(256, 4)
void gate_kernel(const float* __restrict__ x, const float* __restrict__ gW,
                 const float* __restrict__ gb,
                 int* cnt, float* ent_acc, int* bucket, int* topk_e, float* topk_w,
                 unsigned short* __restrict__ xb) {
    __shared__ __align__(16) float gwT[16 * 512];   // [e][d]
    __shared__ float gbs[16];
    __shared__ int lcnt[16];
    __shared__ int gbase[16];
    __shared__ int entpack[64];
    __shared__ float entf;

    int tid = threadIdx.x;
    // stage gW transposed: i -> e = i>>9, d = i&511 (LDS writes conflict-free)
    #pragma unroll
    for (int k = 0; k < 32; ++k) {
        int i = tid + k * 256;
        int e = i >> 9, d = i & 511;
        gwT[e * 512 + d] = gW[d * 16 + e];
    }
    if (tid < 16) { gbs[tid] = gb[tid]; lcnt[tid] = 0; }
    if (tid == 0) entf = 0.f;
    __syncthreads();

    int wave = tid >> 6, lane = tid & 63;
    int ds = lane & 31, rg = lane >> 5;
    int rowbase = blockIdx.x * 32 + wave * 8 + rg;   // rows: rowbase + 2*rr

    float acc[4][16];
    #pragma unroll
    for (int rr = 0; rr < 4; ++rr)
        #pragma unroll
        for (int e = 0; e < 16; ++e) acc[rr][e] = 0.f;

    const float4* gw4 = reinterpret_cast<const float4*>(gwT);
    #pragma unroll
    for (int di = 0; di < 4; ++di) {
        int dbase = ds * 4 + di * 128;
        float4 xv[4];
        #pragma unroll
        for (int rr = 0; rr < 4; ++rr)
            xv[rr] = *reinterpret_cast<const float4*>(x + (size_t)(rowbase + rr * 2) * DDIM + dbase);
        // fused x -> bf16 write
        #pragma unroll
        for (int rr = 0; rr < 4; ++rr) {
            uint2 p;
            p.x = (unsigned)f2bf(xv[rr].x) | ((unsigned)f2bf(xv[rr].y) << 16);
            p.y = (unsigned)f2bf(xv[rr].z) | ((unsigned)f2bf(xv[rr].w) << 16);
            *reinterpret_cast<uint2*>(xb + (size_t)(rowbase + rr * 2) * DDIM + dbase) = p;
        }
        #pragma unroll
        for (int e = 0; e < 16; ++e) {
            float4 g = gw4[e * 128 + (dbase >> 2)];
            #pragma unroll
            for (int rr = 0; rr < 4; ++rr) {
                acc[rr][e] = fmaf(xv[rr].x, g.x, acc[rr][e]);
                acc[rr][e] = fmaf(xv[rr].y, g.y, acc[rr][e]);
                acc[rr][e] = fmaf(xv[rr].z, g.z, acc[rr][e]);
                acc[rr][e] = fmaf(xv[rr].w, g.w, acc[rr][e]);
            }
        }
    }

    // reduce across the 32 d-slice lanes (bits 0..4)
    #pragma unroll
    for (int rr = 0; rr < 4; ++rr)
        #pragma unroll
        for (int e = 0; e < 16; ++e) {
            float v = acc[rr][e];
            v += __shfl_xor(v, 1);  v += __shfl_xor(v, 2);
            v += __shfl_xor(v, 4);  v += __shfl_xor(v, 8);
            v += __shfl_xor(v, 16);
            acc[rr][e] = v;
        }

    if (ds == 0) {
        float entloc = 0.f;
        #pragma unroll
        for (int rr = 0; rr < 4; ++rr) {
            int row = rowbase + rr * 2;
            float sc[16];
            #pragma unroll
            for (int e = 0; e < 16; ++e) sc[e] = acc[rr][e] + gbs[e];
            float v0 = -1e30f, v1 = -1e30f; int i0 = 0, i1 = 0;
            #pragma unroll
            for (int k = 0; k < 16; ++k) {
                float sv = sc[k];
                if (sv > v0) { v1 = v0; i1 = i0; v0 = sv; i0 = k; }
                else if (sv > v1) { v1 = sv; i1 = k; }
            }
            float Z = 0.f, S1 = 0.f;
            #pragma unroll
            for (int k = 0; k < 16; ++k) {
                float t = sc[k] - v0;
                float ex = expf(t);
                Z += ex; S1 = fmaf(ex, t, S1);
            }
            entloc += logf(Z) - S1 / Z;
            float w0 = 1.0f / (1.0f + expf(v1 - v0));
            topk_e[row * 2]     = i0;
            topk_e[row * 2 + 1] = i1;
            topk_w[row * 2]     = w0;
            topk_w[row * 2 + 1] = 1.0f - w0;
            int ib = wave * 8 + rg + rr * 2;
            int lp0 = atomicAdd(&lcnt[i0], 1);
            entpack[ib * 2]     = (row << 1) | (i0 << 15) | (lp0 << 19);
            int lp1 = atomicAdd(&lcnt[i1], 1);
            entpack[ib * 2 + 1] = ((row << 1) | 1) | (i1 << 15) | (lp1 << 19);
        }
        atomicAdd(&entf, entloc);
    }
    __syncthreads();
    if (tid < 16) gbase[tid] = atomicAdd(&cnt[tid], lcnt[tid]);
    if (tid == 0) atomicAdd(ent_acc, entf);
    __syncthreads();
    if (tid < 64) {
        int p = entpack[tid];
        int rowslot = p & 0x7FFF;
        int e = (p >> 15) & 15;
        int lpos = p >> 19;
        bucket[e * BROWS + gbase[e] + lpos] = rowslot;
    }
}

// ---------------- aux loss ----------------
__global__ void aux_kernel(const int* __restrict__ cnt, const float* __restrict__ ent_acc,
                           float* __restrict__ outp) {
    if (threadIdx.x == 0 && blockIdx.x == 0) {
        float lb = 0.f;
        for (int k = 0; k < 16; ++k) {
            float u = (float)cnt[k] * (1.f / 16384.f) - 0.0625f;
            lb += u * u;
        }
        lb *= (1.f / 16.f);
        float ment = ent_acc[0] * (1.f / 16384.f);
        outp[0] = lb - 0.1f * ment;
    }
}

// ---------------- grouped sparse FFN ----------------
// grid.x = NEXP * 256 (tiles of 64 rows); block = 256 (4 waves)
__global__ __launch_bounds__(256, 2)
void ffn_kernel(const unsigned short* __restrict__ xb,
                const unsigned short* __restrict__ w1t,   // [E][H][D] bf16
                const unsigned short* __restrict__ w2t,   // [E][O][H] bf16
                const float* __restrict__ b1, const float* __restrict__ ln_g,
                const float* __restrict__ ln_b,
                const int* __restrict__ cnt, const int* __restrict__ bucket,
                unsigned short* __restrict__ contrib) {
    int e = blockIdx.x >> 8;
    int t = blockIdx.x & 255;
    int n = cnt[e];
    int base = t * 64;
    if (base >= n) return;
    int rows = n - base; if (rows > 64) rows = 64;

    __shared__ __align__(16) char smem[65536];

    int tid = threadIdx.x;
    int wave = tid >> 6, lane = tid & 63;
    int l15 = lane & 15, l4 = lane >> 4;
    const int bbase = e * BROWS + base;

    // ---- stage x tile (64 rows x 512 bf16), XOR-swizzled rows ----
    #pragma unroll
    for (int i = 0; i < 16; ++i) {
        int r = wave * 16 + i;
        int bidx = bbase + ((r < rows) ? r : 0);
        int grow = bucket[bidx] >> 1;
        uint4 v = *reinterpret_cast<const uint4*>(xb + (size_t)grow * DDIM + lane * 8);
        int boff = r * 1024 + ((lane * 16) ^ ((r & 7) << 4));
        *reinterpret_cast<uint4*>(smem + boff) = v;
    }
    __syncthreads();

    // ---- GEMM1: h[64][128] = x_tile @ W1[e] ----
    const unsigned short* w1e = w1t + (size_t)e * HDIM * DDIM;
    f32x4 acc1[4][2];
    #pragma unroll
    for (int r = 0; r < 4; ++r)
        #pragma unroll
        for (int c = 0; c < 2; ++c)
            acc1[r][c] = (f32x4){0.f, 0.f, 0.f, 0.f};

    #pragma unroll
    for (int ks = 0; ks < 16; ++ks) {
        bf16x8 af[4];
        #pragma unroll
        for (int r = 0; r < 4; ++r) {
            int row = r * 16 + l15;
            int boff = row * 1024 + (((ks * 64) + (l4 * 16)) ^ ((row & 7) << 4));
            af[r] = *reinterpret_cast<const bf16x8*>(smem + boff);
        }
        bf16x8 bfg[2];
        #pragma unroll
        for (int c = 0; c < 2; ++c) {
            int col = wave * 32 + c * 16 + l15;
            bfg[c] = *reinterpret_cast<const bf16x8*>(w1e + (size_t)col * DDIM + ks * 32 + l4 * 8);
        }
        #pragma unroll
        for (int r = 0; r < 4; ++r)
            #pragma unroll
            for (int c = 0; c < 2; ++c)
                acc1[r][c] = __builtin_amdgcn_mfma_f32_16x16x32_bf16(af[r], bfg[c], acc1[r][c], 0, 0, 0);
    }
    __syncthreads();   // xs dead; reuse smem

    // ---- bias + exact GELU -> hbuf f32 [64][128] at smem[0..32767] ----
    float* hbuf = reinterpret_cast<float*>(smem);
    const float* b1e = b1 + e * HDIM;
    #pragma unroll
    for (int r = 0; r < 4; ++r)
        #pragma unroll
        for (int c = 0; c < 2; ++c)
            #pragma unroll
            for (int i = 0; i < 4; ++i) {
                int row = r * 16 + l4 * 4 + i;
                int col = wave * 32 + c * 16 + l15;
                float v = acc1[r][c][i] + b1e[col];
                v = 0.5f * v * (1.0f + erff(v * 0.70710678118654752f));
                hbuf[row * 128 + col] = v;
            }
    __syncthreads();

    // ---- LayerNorm over H=128, write bf16 swizzled at smem[32768..49151] ----
    {
        int lrow = tid >> 2, q = tid & 3;
        float s = 0.f, ss = 0.f;
        #pragma unroll
        for (int j = 0; j < 32; ++j) {
            float v = hbuf[lrow * 128 + q + j * 4];
            s += v; ss += v * v;
        }
        s  += __shfl_xor(s, 1);  s  += __shfl_xor(s, 2);
        ss += __shfl_xor(ss, 1); ss += __shfl_xor(ss, 2);
        float mean = s * 0.0078125f;
        float var  = fmaf(-mean, mean, ss * 0.0078125f);
        float rstd = rsqrtf(var + 1e-5f);
        const float* lge = ln_g + e * HDIM;
        const float* lbe = ln_b + e * HDIM;
        #pragma unroll
        for (int j = 0; j < 32; ++j) {
            int col = q + j * 4;
            float v = (hbuf[lrow * 128 + col] - mean) * rstd * lge[col] + lbe[col];
            int boff = 32768 + lrow * 256 + (((col * 2)) ^ ((lrow & 7) << 4));
            *reinterpret_cast<unsigned short*>(smem + boff) = f2bf(v);
        }
    }
    __syncthreads();

    // ---- GEMM2: contrib[64][512] = h_ln @ W2[e]; two column halves ----
    const unsigned short* w2e = w2t + (size_t)e * ODIM * HDIM;
    #pragma unroll 1
    for (int half = 0; half < 2; ++half) {
        f32x4 acc2[4][4];
        #pragma unroll
        for (int r = 0; r < 4; ++r)
            #pragma unroll
            for (int c = 0; c < 4; ++c)
                acc2[r][c] = (f32x4){0.f, 0.f, 0.f, 0.f};

        #pragma unroll
        for (int ks = 0; ks < 4; ++ks) {
            bf16x8 af[4];
            #pragma unroll
            for (int r = 0; r < 4; ++r) {
                int row = r * 16 + l15;
                int boff = 32768 + row * 256 + (((ks * 64) + (l4 * 16)) ^ ((row & 7) << 4));
                af[r] = *reinterpret_cast<const bf16x8*>(smem + boff);
            }
            bf16x8 bfg[4];
            #pragma unroll
            for (int c = 0; c < 4; ++c) {
                int col = wave * 128 + half * 64 + c * 16 + l15;
                bfg[c] = *reinterpret_cast<const bf16x8*>(w2e + (size_t)col * HDIM + ks * 32 + l4 * 8);
            }
            #pragma unroll
            for (int r = 0; r < 4; ++r)
                #pragma unroll
                for (int c = 0; c < 4; ++c)
                    acc2[r][c] = __builtin_amdgcn_mfma_f32_16x16x32_bf16(af[r], bfg[c], acc2[r][c], 0, 0, 0);
        }
        // epilogue: store raw contributions (weights applied in combine)
        #pragma unroll
        for (int r = 0; r < 4; ++r)
            #pragma unroll
            for (int i = 0; i < 4; ++i) {
                int lrow = r * 16 + l4 * 4 + i;
                if (lrow < rows) {
                    int rs = bucket[bbase + lrow];   // (row<<1)|slot
                    #pragma unroll
                    for (int c = 0; c < 4; ++c) {
                        int col = wave * 128 + half * 64 + c * 16 + l15;
                        contrib[(size_t)rs * ODIM + col] = f2bf(acc2[r][c][i]);
                    }
                }
            }
    }
}

// ---------------- combine top-2 ----------------
__global__ __launch_bounds__(256)
void combine_kernel(const unsigned short* __restrict__ contrib, const int* __restrict__ topk_e,
                    const float* __restrict__ topk_w, const float* __restrict__ b2,
                    float* __restrict__ out) {
    int idx = blockIdx.x * 256 + threadIdx.x;
    int row = idx >> 6;
    int cb = (idx & 63) << 3;
    float w0 = topk_w[row * 2], w1 = topk_w[row * 2 + 1];
    int e0 = topk_e[row * 2], e1 = topk_e[row * 2 + 1];
    bf16x8 c0 = *reinterpret_cast<const bf16x8*>(contrib + (size_t)row * 1024 + cb);
    bf16x8 c1 = *reinterpret_cast<const bf16x8*>(contrib + (size_t)row * 1024 + 512 + cb);
    const float* b20 = b2 + e0 * ODIM + cb;
    const float* b21 = b2 + e1 * ODIM + cb;
    float res[8];
    #pragma unroll
    for (int j = 0; j < 8; ++j)
        res[j] = w0 * (bf2f((unsigned short)c0[j]) + b20[j]) + w1 * (bf2f((unsigned short)c1[j]) + b21[j]);
    float4 o0 = {res[0], res[1], res[2], res[3]};
    float4 o1 = {res[4], res[5], res[6], res[7]};
    *reinterpret_cast<float4*>(out + (size_t)row * ODIM + cb) = o0;
    *reinterpret_cast<float4*>(out + (size_t)row * ODIM + cb + 4) = o1;
}

extern "C" void kernel_launch(void* const* d_in, const int* in_sizes, int n_in,
                              void* d_out, int out_size, void* d_ws, size_t ws_size,
                              hipStream_t stream) {
    const float* x    = (const float*)d_in[0];
    const float* gW   = (const float*)d_in[1];
    const float* gb   = (const float*)d_in[2];
    const float* W1   = (const float*)d_in[3];
    const float* b1   = (const float*)d_in[4];
    const float* ln_g = (const float*)d_in[5];
    const float* ln_b = (const float*)d_in[6];
    const float* W2   = (const float*)d_in[7];
    const float* b2   = (const float*)d_in[8];
    float* out = (float*)d_out;

    char* ws = (char*)d_ws;
    int*   cnt     = (int*)(ws);                       // 64 B
    float* ent_acc = (float*)(ws + 64);                // 4 B
    int*   topk_e  = (int*)(ws + 256);                 // 128 KB
    float* topk_w  = (float*)(ws + 256 + 131072);      // 128 KB
    int*   bucket  = (int*)(ws + 262400);              // 1 MB
    unsigned short* xb      = (unsigned short*)(ws + 1310976);   // 16 MB
    unsigned short* w1t     = (unsigned short*)(ws + 18088192);  // 2 MB
    unsigned short* w2t     = (unsigned short*)(ws + 20185344);  // 2 MB
    unsigned short* contrib = (unsigned short*)(ws + 22282496);  // 32 MB

    hipMemsetAsync(ws, 0, 256, stream);

    transpose_to_bf16<<<dim3(HDIM / 32, DDIM / 32, NEXP), dim3(32, 8), 0, stream>>>(W1, w1t, DDIM, HDIM);
    transpose_to_bf16<<<dim3(ODIM / 32, HDIM / 32, NEXP), dim3(32, 8), 0, stream>>>(W2, w2t, HDIM, ODIM);
    gate_kernel<<<BROWS / 32, 256, 0, stream>>>(x, gW, gb, cnt, ent_acc, bucket, topk_e, topk_w, xb);
    aux_kernel<<<1, 64, 0, stream>>>(cnt, ent_acc, out + (out_size - 1));
    ffn_kernel<<<NEXP * 256, 256, 0, stream>>>(xb, w1t, w2t, b1, ln_g, ln_b, cnt, bucket, contrib);
    combine_kernel<<<(BROWS * ODIM / 8) / 256, 256, 0, stream>>>(contrib, topk_e, topk_w, b2, out);
}

// Round 3
// 113.265 us; speedup vs baseline: 1.9630x; 1.1580x over previous
//
#include <hip/hip_runtime.h>

#define BROWS 16384
#define DDIM  512
#define NEXP  16
#define HDIM  128
#define ODIM  512

typedef __attribute__((ext_vector_type(8))) short bf16x8;
typedef __attribute__((ext_vector_type(4))) float f32x4;

typedef const __attribute__((address_space(1))) unsigned GA;
typedef __attribute__((address_space(3))) unsigned LA;
#define GLD16(g, l) __builtin_amdgcn_global_load_lds((GA*)(g), (LA*)(l), 16, 0, 0)

static __device__ __forceinline__ unsigned short f2bf(float f) {
    union { float f; unsigned u; } v; v.f = f;
    unsigned r = v.u + 0x7fffu + ((v.u >> 16) & 1u);
    return (unsigned short)(r >> 16);
}
static __device__ __forceinline__ float bf2f(unsigned short h) {
    union { unsigned u; float f; } v; v.u = ((unsigned)h) << 16;
    return v.f;
}

// ---------------- W1 -> blocked bf16 [e][ks=8][c=128][k=64] ----------------
__global__ __launch_bounds__(256)
void w1_prep(const float* __restrict__ in, unsigned short* __restrict__ out) {
    __shared__ float tile[64][33];
    int e = blockIdx.z;
    int ks = blockIdx.y;
    int cb = blockIdx.x * 32;
    const float* src = in + ((size_t)e * 512 + ks * 64) * 128 + cb;
    int c = threadIdx.x & 31, r8 = threadIdx.x >> 5;
    #pragma unroll
    for (int p = 0; p < 8; ++p)
        tile[p * 8 + r8][c] = src[(size_t)(p * 8 + r8) * 128 + c];
    __syncthreads();
    int k = threadIdx.x & 63, c4 = threadIdx.x >> 6;
    unsigned short* dst = out + (((size_t)e * 8 + ks) * 128 + cb) * 64;
    #pragma unroll
    for (int p = 0; p < 8; ++p)
        dst[(size_t)(c4 + p * 4) * 64 + k] = f2bf(tile[k][c4 + p * 4]);
}

// ---------------- transpose W2 to bf16 [e][O][H] ----------------
__global__ __launch_bounds__(256)
void transpose_to_bf16(const float* __restrict__ in, unsigned short* __restrict__ out, int R, int C) {
    __shared__ float tile[32][33];
    int e = blockIdx.z;
    in  += (size_t)e * R * C;
    out += (size_t)e * R * C;
    int c0 = blockIdx.x * 32, r0 = blockIdx.y * 32;
    for (int i = threadIdx.y; i < 32; i += 8)
        tile[i][threadIdx.x] = in[(size_t)(r0 + i) * C + c0 + threadIdx.x];
    __syncthreads();
    for (int i = threadIdx.y; i < 32; i += 8)
        out[(size_t)(c0 + i) * R + r0 + threadIdx.x] = f2bf(tile[threadIdx.x][i]);
}

// ---------------- gating (fused with x->bf16 conversion) ----------------
__global__ __launch_bounds__(256, 4)
void gate_kernel(const float* __restrict__ x, const float* __restrict__ gW,
                 const float* __restrict__ gb,
                 int* cnt, float* ent_acc, int* bucket, int* topk_e, float* topk_w,
                 unsigned short* __restrict__ xb) {
    __shared__ __align__(16) float gwT[16 * 512];   // [e][d]
    __shared__ float gbs[16];
    __shared__ int lcnt[16];
    __shared__ int gbase[16];
    __shared__ int entpack[64];
    __shared__ float entf;

    int tid = threadIdx.x;
    #pragma unroll
    for (int k = 0; k < 32; ++k) {
        int i = tid + k * 256;
        int e = i >> 9, d = i & 511;
        gwT[e * 512 + d] = gW[d * 16 + e];
    }
    if (tid < 16) { gbs[tid] = gb[tid]; lcnt[tid] = 0; }
    if (tid == 0) entf = 0.f;
    __syncthreads();

    int wave = tid >> 6, lane = tid & 63;
    int ds = lane & 31, rg = lane >> 5;
    int rowbase = blockIdx.x * 32 + wave * 8 + rg;

    float acc[4][16];
    #pragma unroll
    for (int rr = 0; rr < 4; ++rr)
        #pragma unroll
        for (int e = 0; e < 16; ++e) acc[rr][e] = 0.f;

    const float4* gw4 = reinterpret_cast<const float4*>(gwT);
    #pragma unroll
    for (int di = 0; di < 4; ++di) {
        int dbase = ds * 4 + di * 128;
        float4 xv[4];
        #pragma unroll
        for (int rr = 0; rr < 4; ++rr)
            xv[rr] = *reinterpret_cast<const float4*>(x + (size_t)(rowbase + rr * 2) * DDIM + dbase);
        #pragma unroll
        for (int rr = 0; rr < 4; ++rr) {
            uint2 p;
            p.x = (unsigned)f2bf(xv[rr].x) | ((unsigned)f2bf(xv[rr].y) << 16);
            p.y = (unsigned)f2bf(xv[rr].z) | ((unsigned)f2bf(xv[rr].w) << 16);
            *reinterpret_cast<uint2*>(xb + (size_t)(rowbase + rr * 2) * DDIM + dbase) = p;
        }
        #pragma unroll
        for (int e = 0; e < 16; ++e) {
            float4 g = gw4[e * 128 + (dbase >> 2)];
            #pragma unroll
            for (int rr = 0; rr < 4; ++rr) {
                acc[rr][e] = fmaf(xv[rr].x, g.x, acc[rr][e]);
                acc[rr][e] = fmaf(xv[rr].y, g.y, acc[rr][e]);
                acc[rr][e] = fmaf(xv[rr].z, g.z, acc[rr][e]);
                acc[rr][e] = fmaf(xv[rr].w, g.w, acc[rr][e]);
            }
        }
    }

    #pragma unroll
    for (int rr = 0; rr < 4; ++rr)
        #pragma unroll
        for (int e = 0; e < 16; ++e) {
            float v = acc[rr][e];
            v += __shfl_xor(v, 1);  v += __shfl_xor(v, 2);
            v += __shfl_xor(v, 4);  v += __shfl_xor(v, 8);
            v += __shfl_xor(v, 16);
            acc[rr][e] = v;
        }

    if (ds == 0) {
        float entloc = 0.f;
        #pragma unroll
        for (int rr = 0; rr < 4; ++rr) {
            int row = rowbase + rr * 2;
            float sc[16];
            #pragma unroll
            for (int e = 0; e < 16; ++e) sc[e] = acc[rr][e] + gbs[e];
            float v0 = -1e30f, v1 = -1e30f; int i0 = 0, i1 = 0;
            #pragma unroll
            for (int k = 0; k < 16; ++k) {
                float sv = sc[k];
                if (sv > v0) { v1 = v0; i1 = i0; v0 = sv; i0 = k; }
                else if (sv > v1) { v1 = sv; i1 = k; }
            }
            float Z = 0.f, S1 = 0.f;
            #pragma unroll
            for (int k = 0; k < 16; ++k) {
                float t = sc[k] - v0;
                float ex = expf(t);
                Z += ex; S1 = fmaf(ex, t, S1);
            }
            entloc += logf(Z) - S1 / Z;
            float w0 = 1.0f / (1.0f + expf(v1 - v0));
            topk_e[row * 2]     = i0;
            topk_e[row * 2 + 1] = i1;
            topk_w[row * 2]     = w0;
            topk_w[row * 2 + 1] = 1.0f - w0;
            int ib = wave * 8 + rg + rr * 2;
            int lp0 = atomicAdd(&lcnt[i0], 1);
            entpack[ib * 2]     = (row << 1) | (i0 << 15) | (lp0 << 19);
            int lp1 = atomicAdd(&lcnt[i1], 1);
            entpack[ib * 2 + 1] = ((row << 1) | 1) | (i1 << 15) | (lp1 << 19);
        }
        atomicAdd(&entf, entloc);
    }
    __syncthreads();
    if (tid < 16) gbase[tid] = atomicAdd(&cnt[tid], lcnt[tid]);
    if (tid == 0) atomicAdd(ent_acc, entf);
    __syncthreads();
    if (tid < 64) {
        int p = entpack[tid];
        int rowslot = p & 0x7FFF;
        int e = (p >> 15) & 15;
        int lpos = p >> 19;
        bucket[e * BROWS + gbase[e] + lpos] = rowslot;
    }
}

// ---------------- aux loss ----------------
__global__ void aux_kernel(const int* __restrict__ cnt, const float* __restrict__ ent_acc,
                           float* __restrict__ outp) {
    if (threadIdx.x == 0 && blockIdx.x == 0) {
        float lb = 0.f;
        for (int k = 0; k < 16; ++k) {
            float u = (float)cnt[k] * (1.f / 16384.f) - 0.0625f;
            lb += u * u;
        }
        lb *= (1.f / 16.f);
        float ment = ent_acc[0] * (1.f / 16384.f);
        outp[0] = lb - 0.1f * ment;
    }
}

// ---------------- grouped sparse FFN, pipelined ----------------
// grid = NEXP*64 tiles of 64 rows; 256 threads (4 waves).
// LDS map: [0,16384) A-dbuf (2x8KB) -> later h_ln (16KB) -> GEMM2 patches (4x3KB)
//          [16384,49152) B dbuf (2x16KB)
//          [49152,51200) LN partials   [51200,51456) rowinfo rs   [51456,51712) wgt
__global__ __launch_bounds__(256, 2)
void ffn_kernel(const unsigned short* __restrict__ xb,
                const unsigned short* __restrict__ w1b,   // [E][8][128][64] bf16
                const unsigned short* __restrict__ w2t,   // [E][O][H] bf16
                const float* __restrict__ b1, const float* __restrict__ ln_g,
                const float* __restrict__ ln_b, const float* __restrict__ topk_w,
                const int* __restrict__ cnt, const int* __restrict__ bucket,
                unsigned short* __restrict__ contrib) {
    int e = blockIdx.x >> 6;
    int t = blockIdx.x & 63;
    int n = cnt[e];
    int base = t * 64;
    if (base >= n) return;
    int rows = n - base; if (rows > 64) rows = 64;

    __shared__ __align__(16) char smem[51712];

    const int tid = threadIdx.x;
    const int wave = tid >> 6, lane = tid & 63;
    const int l15 = lane & 15, l4 = lane >> 4;
    const int bbase = e * BROWS + base;

    if (tid < 64) {
        int idx = tid < rows ? tid : (rows - 1);
        int rs = bucket[bbase + idx];
        *(int*)(smem + 51200 + tid * 4) = rs;
        *(float*)(smem + 51456 + tid * 4) = topk_w[rs];
    }

    const int lsw = (((lane & 7) ^ ((lane >> 3) & 7)) << 4);
    int ar0 = wave * 16 + (lane >> 3);
    int ar1 = ar0 + 8;
    size_t grow0 = (size_t)(bucket[bbase + (ar0 < rows ? ar0 : rows - 1)] >> 1) * 1024;
    size_t grow1 = (size_t)(bucket[bbase + (ar1 < rows ? ar1 : rows - 1)] >> 1) * 1024;
    const char* xbp = (const char*)xb;
    const char* w1e = (const char*)w1b + (size_t)e * 131072;
    const char* w2e = (const char*)w2t + (size_t)e * 131072;
    const int sw2e = (((lane & 15) ^ (lane >> 4)) << 4);
    const int sw2o = sw2e ^ 64;

#define STAGE1(ks_, buf_) do { \
    char* ab_ = smem + (buf_) * 8192; \
    char* bb_ = smem + 16384 + (buf_) * 16384; \
    GLD16(xbp + grow0 + (ks_) * 128 + lsw, ab_ + (wave * 2 + 0) * 1024); \
    GLD16(xbp + grow1 + (ks_) * 128 + lsw, ab_ + (wave * 2 + 1) * 1024); \
    const char* s1_ = w1e + (ks_) * 16384 + ((lane >> 3) << 7) + lsw; \
    GLD16(s1_ + (wave * 4 + 0) * 1024, bb_ + (wave * 4 + 0) * 1024); \
    GLD16(s1_ + (wave * 4 + 1) * 1024, bb_ + (wave * 4 + 1) * 1024); \
    GLD16(s1_ + (wave * 4 + 2) * 1024, bb_ + (wave * 4 + 2) * 1024); \
    GLD16(s1_ + (wave * 4 + 3) * 1024, bb_ + (wave * 4 + 3) * 1024); \
} while (0)

#define STAGE2(ns_, buf_) do { \
    char* bb_ = smem + 16384 + (buf_) * 16384; \
    const char* s2_ = w2e + (size_t)(ns_) * 16384 + ((lane >> 4) << 8); \
    GLD16(s2_ + (wave * 4 + 0) * 1024 + sw2e, bb_ + (wave * 4 + 0) * 1024); \
    GLD16(s2_ + (wave * 4 + 1) * 1024 + sw2o, bb_ + (wave * 4 + 1) * 1024); \
    GLD16(s2_ + (wave * 4 + 2) * 1024 + sw2e, bb_ + (wave * 4 + 2) * 1024); \
    GLD16(s2_ + (wave * 4 + 3) * 1024 + sw2o, bb_ + (wave * 4 + 3) * 1024); \
} while (0)

    // ================= GEMM1: h = x_tile @ W1[e] =================
    STAGE1(0, 0);
    f32x4 acc1[4][2];
    #pragma unroll
    for (int r = 0; r < 4; ++r)
        #pragma unroll
        for (int c = 0; c < 2; ++c)
            acc1[r][c] = (f32x4){0.f, 0.f, 0.f, 0.f};

    #pragma unroll
    for (int ks = 0; ks < 8; ++ks) {
        const int cur = ks & 1;
        if (ks < 7) {
            STAGE1(ks + 1, cur ^ 1);
            asm volatile("s_waitcnt vmcnt(6)" ::: "memory");
        } else {
            asm volatile("s_waitcnt vmcnt(0)" ::: "memory");
        }
        asm volatile("s_barrier" ::: "memory");
        const char* ab = smem + cur * 8192;
        const char* bb = smem + 16384 + cur * 16384;
        #pragma unroll
        for (int ks2 = 0; ks2 < 2; ++ks2) {
            const int cb = (((ks2 * 4 + l4) ^ (l15 & 7)) << 4);
            bf16x8 a[4], bg[2];
            #pragma unroll
            for (int r = 0; r < 4; ++r)
                a[r] = *(const bf16x8*)(ab + (r * 16 + l15) * 128 + cb);
            bg[0] = *(const bf16x8*)(bb + (wave * 32 + l15) * 128 + cb);
            bg[1] = *(const bf16x8*)(bb + (wave * 32 + 16 + l15) * 128 + cb);
            #pragma unroll
            for (int r = 0; r < 4; ++r) {
                acc1[r][0] = __builtin_amdgcn_mfma_f32_16x16x32_bf16(a[r], bg[0], acc1[r][0], 0, 0, 0);
                acc1[r][1] = __builtin_amdgcn_mfma_f32_16x16x32_bf16(a[r], bg[1], acc1[r][1], 0, 0, 0);
            }
        }
        asm volatile("s_waitcnt lgkmcnt(0)\n\ts_barrier" ::: "memory");
    }

    // kick off first W2 slice while we do GELU/LN
    STAGE2(0, 0);

    // ================= bias + exact GELU (in regs) + LN partials =================
    const float* b1e = b1 + e * HDIM;
    const int c0 = wave * 32 + l15, c1 = c0 + 16;
    float bias0 = b1e[c0], bias1 = b1e[c1];
    #pragma unroll
    for (int r = 0; r < 4; ++r)
        #pragma unroll
        for (int i = 0; i < 4; ++i) {
            int row = r * 16 + l4 * 4 + i;
            float v0 = acc1[r][0][i] + bias0;
            float v1 = acc1[r][1][i] + bias1;
            v0 = 0.5f * v0 * (1.0f + erff(v0 * 0.70710678f));
            v1 = 0.5f * v1 * (1.0f + erff(v1 * 0.70710678f));
            acc1[r][0][i] = v0; acc1[r][1][i] = v1;
            float s = v0 + v1, ss = v0 * v0 + v1 * v1;
            s  += __shfl_xor(s, 1);  s  += __shfl_xor(s, 2);
            s  += __shfl_xor(s, 4);  s  += __shfl_xor(s, 8);
            ss += __shfl_xor(ss, 1); ss += __shfl_xor(ss, 2);
            ss += __shfl_xor(ss, 4); ss += __shfl_xor(ss, 8);
            if (l15 == 0) {
                *(float*)(smem + 49152 + row * 32 + wave * 8)     = s;
                *(float*)(smem + 49152 + row * 32 + wave * 8 + 4) = ss;
            }
        }
    asm volatile("s_waitcnt lgkmcnt(0)\n\ts_barrier" ::: "memory");

    // ================= LN apply (gate weight folded in) -> h_ln bf16 swizzled =================
    {
        const float* lge = ln_g + e * HDIM;
        const float* lbe = ln_b + e * HDIM;
        float g0 = lge[c0], g1 = lge[c1], be0 = lbe[c0], be1 = lbe[c1];
        #pragma unroll
        for (int r = 0; r < 4; ++r)
            #pragma unroll
            for (int i = 0; i < 4; ++i) {
                int row = r * 16 + l4 * 4 + i;
                float4 p0 = *(const float4*)(smem + 49152 + row * 32);
                float4 p1 = *(const float4*)(smem + 49152 + row * 32 + 16);
                float s  = p0.x + p0.z + p1.x + p1.z;
                float ss = p0.y + p0.w + p1.y + p1.w;
                float mean = s * 0.0078125f;
                float var  = fmaf(-mean, mean, ss * 0.0078125f);
                float rstd = rsqrtf(var + 1e-5f);
                float w = *(const float*)(smem + 51456 + row * 4);
                float h0 = ((acc1[r][0][i] - mean) * rstd * g0 + be0) * w;
                float h1 = ((acc1[r][1][i] - mean) * rstd * g1 + be1) * w;
                int wr = (row & 7) << 4;
                *(unsigned short*)(smem + row * 256 + ((c0 * 2) ^ wr)) = f2bf(h0);
                *(unsigned short*)(smem + row * 256 + ((c1 * 2) ^ wr)) = f2bf(h1);
            }
    }
    asm volatile("s_waitcnt lgkmcnt(0)\n\ts_barrier" ::: "memory");

    // ================= hoist GEMM2 A fragments to registers =================
    bf16x8 A2[4][4];
    #pragma unroll
    for (int r = 0; r < 4; ++r)
        #pragma unroll
        for (int kk = 0; kk < 4; ++kk)
            A2[r][kk] = *(const bf16x8*)(smem + (r * 16 + l15) * 256 + ((((kk * 4 + l4) ^ (l15 & 7))) << 4));
    asm volatile("s_waitcnt lgkmcnt(0)\n\ts_barrier" ::: "memory");   // h_ln region now reusable as patches

    // ================= GEMM2: contrib = h_ln @ W2[e], barrier-free =================
    STAGE2(1, 1);
    char* patch = smem + wave * 3072;   // 64 rows x 48B (16 cols bf16 + pad)
    const int rsoff = (*(const int*)(smem + 51200 + lane * 4)) << 10;
    char* cw = (char*)contrib + rsoff + wave * 32;

    #pragma unroll
    for (int ns = 0; ns < 8; ++ns) {
        if (ns < 7) {
            asm volatile("s_waitcnt lgkmcnt(0)" ::: "memory");
            if (ns > 0) STAGE2(ns + 1, (ns + 1) & 1);
        }
        if (ns == 0)      asm volatile("s_waitcnt vmcnt(4)" ::: "memory");
        else if (ns < 7)  asm volatile("s_waitcnt vmcnt(6)" ::: "memory");
        else              asm volatile("s_waitcnt vmcnt(2)" ::: "memory");

        const char* bb = smem + 16384 + (ns & 1) * 16384;
        bf16x8 Bf[4];
        #pragma unroll
        for (int kk = 0; kk < 4; ++kk)
            Bf[kk] = *(const bf16x8*)(bb + (wave * 16 + l15) * 256 + ((((kk * 4 + l4) ^ (l15 & 7))) << 4));

        f32x4 acc2[4];
        #pragma unroll
        for (int r = 0; r < 4; ++r) acc2[r] = (f32x4){0.f, 0.f, 0.f, 0.f};
        #pragma unroll
        for (int kk = 0; kk < 4; ++kk)
            #pragma unroll
            for (int r = 0; r < 4; ++r)
                acc2[r] = __builtin_amdgcn_mfma_f32_16x16x32_bf16(A2[r][kk], Bf[kk], acc2[r], 0, 0, 0);

        // epilogue through per-wave LDS patch -> 2 vector stores
        #pragma unroll
        for (int r = 0; r < 4; ++r)
            #pragma unroll
            for (int i = 0; i < 4; ++i)
                *(unsigned short*)(patch + (r * 16 + l4 * 4 + i) * 48 + l15 * 2) = f2bf(acc2[r][i]);
        bf16x8 p0 = *(const bf16x8*)(patch + lane * 48);
        bf16x8 p1 = *(const bf16x8*)(patch + lane * 48 + 16);
        *(bf16x8*)(cw + ns * 128)      = p0;
        *(bf16x8*)(cw + ns * 128 + 16) = p1;
    }
#undef STAGE1
#undef STAGE2
}

// ---------------- combine top-2 ----------------
__global__ __launch_bounds__(256)
void combine_kernel(const unsigned short* __restrict__ contrib, const int* __restrict__ topk_e,
                    const float* __restrict__ topk_w, const float* __restrict__ b2,
                    float* __restrict__ out) {
    int idx = blockIdx.x * 256 + threadIdx.x;
    int row = idx >> 6;
    int cb = (idx & 63) << 3;
    int e0 = topk_e[row * 2], e1 = topk_e[row * 2 + 1];
    float w0 = topk_w[row * 2], w1 = topk_w[row * 2 + 1];
    bf16x8 c0 = *reinterpret_cast<const bf16x8*>(contrib + (size_t)row * 1024 + cb);
    bf16x8 c1 = *reinterpret_cast<const bf16x8*>(contrib + (size_t)row * 1024 + 512 + cb);
    const float* b20 = b2 + e0 * ODIM + cb;
    const float* b21 = b2 + e1 * ODIM + cb;
    float res[8];
    #pragma unroll
    for (int j = 0; j < 8; ++j)
        res[j] = bf2f((unsigned short)c0[j]) + bf2f((unsigned short)c1[j]) + w0 * b20[j] + w1 * b21[j];
    float4 o0 = {res[0], res[1], res[2], res[3]};
    float4 o1 = {res[4], res[5], res[6], res[7]};
    *reinterpret_cast<float4*>(out + (size_t)row * ODIM + cb) = o0;
    *reinterpret_cast<float4*>(out + (size_t)row * ODIM + cb + 4) = o1;
}

extern "C" void kernel_launch(void* const* d_in, const int* in_sizes, int n_in,
                              void* d_out, int out_size, void* d_ws, size_t ws_size,
                              hipStream_t stream) {
    const float* x    = (const float*)d_in[0];
    const float* gW   = (const float*)d_in[1];
    const float* gb   = (const float*)d_in[2];
    const float* W1   = (const float*)d_in[3];
    const float* b1   = (const float*)d_in[4];
    const float* ln_g = (const float*)d_in[5];
    const float* ln_b = (const float*)d_in[6];
    const float* W2   = (const float*)d_in[7];
    const float* b2   = (const float*)d_in[8];
    float* out = (float*)d_out;

    char* ws = (char*)d_ws;
    int*   cnt     = (int*)(ws);
    float* ent_acc = (float*)(ws + 64);
    int*   topk_e  = (int*)(ws + 256);
    float* topk_w  = (float*)(ws + 256 + 131072);
    int*   bucket  = (int*)(ws + 262400);
    unsigned short* xb      = (unsigned short*)(ws + 1310976);   // 16 MB
    unsigned short* w1b     = (unsigned short*)(ws + 18088192);  // 2 MB (blocked W1)
    unsigned short* w2t     = (unsigned short*)(ws + 20185344);  // 2 MB
    unsigned short* contrib = (unsigned short*)(ws + 22282496);  // 32 MB

    hipMemsetAsync(ws, 0, 256, stream);

    w1_prep<<<dim3(4, 8, NEXP), 256, 0, stream>>>(W1, w1b);
    transpose_to_bf16<<<dim3(ODIM / 32, HDIM / 32, NEXP), dim3(32, 8), 0, stream>>>(W2, w2t, HDIM, ODIM);
    gate_kernel<<<BROWS / 32, 256, 0, stream>>>(x, gW, gb, cnt, ent_acc, bucket, topk_e, topk_w, xb);
    aux_kernel<<<1, 64, 0, stream>>>(cnt, ent_acc, out + (out_size - 1));
    ffn_kernel<<<NEXP * 64, 256, 0, stream>>>(xb, w1b, w2t, b1, ln_g, ln_b, topk_w, cnt, bucket, contrib);
    combine_kernel<<<(BROWS * ODIM / 8) / 256, 256, 0, stream>>>(contrib, topk_e, topk_w, b2, out);
}